// Round 8
// baseline (215.870 us; speedup 1.0000x reference)
//
#include <hip/hip_runtime.h>
#include <stdint.h>

typedef __bf16 bf16;
typedef __attribute__((ext_vector_type(8))) __bf16 bf16x8;
typedef __attribute__((ext_vector_type(4))) __bf16 bf16x4;
typedef __attribute__((ext_vector_type(4))) float  f32x4;

#define ATT_SCALE 0.125f   // 1/sqrt(64), folded into Q at GEMM epilogue

// ---------------------------------------------------------------------------
// async 16B global -> LDS (wave-uniform LDS base + lane*16, per-lane gaddr)
// ---------------------------------------------------------------------------
__device__ __forceinline__ void async16(void* lds, const void* g) {
  __builtin_amdgcn_global_load_lds(
      (__attribute__((address_space(1))) void*)(void*)g,
      (__attribute__((address_space(3))) void*)lds,
      16, 0, 0);
}

// ---------------------------------------------------------------------------
// Fused prep: blocks [0,3072) convert x fp32->bf16 (8 elems/thread);
//             blocks [3072,4800) transpose W [768x2304] fp32 -> Wt bf16.
// ---------------------------------------------------------------------------
__global__ void prep_kernel(const float* __restrict__ x, bf16* __restrict__ y,
                            const float* __restrict__ W, bf16* __restrict__ Wt) {
  __shared__ float tile[32][33];
  const int tid = threadIdx.x;
  if (blockIdx.x < 3072) {
    size_t i = ((size_t)blockIdx.x * 256 + tid) * 8;
    float4 a = *(const float4*)(x + i);
    float4 b = *(const float4*)(x + i + 4);
    bf16x8 o;
    o[0] = (bf16)a.x; o[1] = (bf16)a.y; o[2] = (bf16)a.z; o[3] = (bf16)a.w;
    o[4] = (bf16)b.x; o[5] = (bf16)b.y; o[6] = (bf16)b.z; o[7] = (bf16)b.w;
    *(bf16x8*)(y + i) = o;
  } else {
    const int bid = blockIdx.x - 3072;        // 0..1727
    const int tx = tid & 31, ty = tid >> 5;   // 32 x 8
    const int n0 = (bid % 72) * 32, k0 = (bid / 72) * 32;
#pragma unroll
    for (int r = 0; r < 4; ++r)
      tile[ty + r * 8][tx] = W[(size_t)(k0 + ty + r * 8) * 2304 + n0 + tx];
    __syncthreads();
#pragma unroll
    for (int r = 0; r < 4; ++r)
      Wt[(size_t)(n0 + ty + r * 8) * 768 + k0 + tx] = (bf16)tile[tx][ty + r * 8];
  }
}

// ---------------------------------------------------------------------------
// QKV GEMM v3 (unchanged from R6, 42.3 us steady): 128x128 tile, BK=64,
//   XCD swizzle (FETCH 70->48 MB), counted-vmcnt two-barrier K-loop.
// ---------------------------------------------------------------------------
__global__ void qkv_gemm_kernel(const bf16* __restrict__ A, const bf16* __restrict__ Bw,
                                const float* __restrict__ bias,
                                bf16* __restrict__ Qo, bf16* __restrict__ Ko,
                                bf16* __restrict__ Vo) {
  __shared__ __align__(16) char lds[65536];   // 2 x (A 16KB + B 16KB)

  const int tid  = threadIdx.x;
  const int wave = tid >> 6, lane = tid & 63;
  const int quad = lane >> 4, mn = lane & 15;
  const int wr = wave >> 1, wc = wave & 1;

  // XCD swizzle: orig dispatch id -> contiguous per-XCD chunk (144 blocks)
  const int orig = blockIdx.y * 18 + blockIdx.x;   // hw flat id (x fastest)
  const int swz  = (orig & 7) * 144 + (orig >> 3); // 1152 = 8 * 144, bijective
  const int m0 = (swz / 18) * 128;
  const int n0 = (swz % 18) * 128;

  f32x4 acc[4][4] = {};

  const int lrow = lane >> 3;           // 0..7  (row within 8-row group)
  const int cg   = (lane & 7) ^ lrow;   // global 16B-chunk index (swizzled)

  auto stage = [&](int kt, char* buf) {
    char* Al = buf;
    char* Bl = buf + 16384;
#pragma unroll
    for (int u = 0; u < 4; ++u) {
      const int t   = wave * 4 + u;      // 8-row group 0..15
      const int row = t * 8 + lrow;      // tile row 0..127
      async16(Al + t * 1024 + lane * 16,
              A  + (size_t)(m0 + row) * 768 + kt + cg * 8);
      async16(Bl + t * 1024 + lane * 16,
              Bw + (size_t)(n0 + row) * 768 + kt + cg * 8);
    }
  };

#define SCHED0() __builtin_amdgcn_sched_barrier(0)

  stage(0, lds); SCHED0();

  for (int j = 0; j < 12; ++j) {
    // BAR-A: all waves finished iter j-1 LDS reads (WAR gate for buf (j+1)&1)
    asm volatile("s_waitcnt lgkmcnt(0)" ::: "memory"); SCHED0();
    __builtin_amdgcn_s_barrier(); SCHED0();
    if (j < 11) { stage((j + 1) * 64, lds + ((j + 1) & 1) * 32768); SCHED0(); }
    // complete own stage j (8 loads); leave stage j+1 in flight
    if (j < 11) { asm volatile("s_waitcnt vmcnt(8)" ::: "memory"); }
    else        { asm volatile("s_waitcnt vmcnt(0)" ::: "memory"); }
    SCHED0();
    __builtin_amdgcn_s_barrier(); SCHED0();   // BAR-B: publish stage j

    char* Al = lds + (j & 1) * 32768;
    char* Bl = Al + 16384;

#pragma unroll
    for (int s = 0; s < 2; ++s) {        // two K=32 steps within BK=64
      bf16x8 af[4], bfr[4];
      const int csw = ((s * 4 + quad) ^ (mn & 7)) * 16;  // swizzled chunk offset
#pragma unroll
      for (int i = 0; i < 4; ++i) {
        af[i]  = *(const bf16x8*)(Al + (wr * 64 + i * 16 + mn) * 128 + csw);
        bfr[i] = *(const bf16x8*)(Bl + (wc * 64 + i * 16 + mn) * 128 + csw);
      }
#pragma unroll
      for (int i = 0; i < 4; ++i)
#pragma unroll
        for (int jj = 0; jj < 4; ++jj)
          acc[i][jj] = __builtin_amdgcn_mfma_f32_16x16x32_bf16(af[i], bfr[jj], acc[i][jj], 0, 0, 0);
    }
  }

#undef SCHED0

  // epilogue
  const int ng    = n0 + wc * 64;
  const int third = ng / 768;           // 0=Q 1=K 2=V
  const int nmod  = ng % 768;
  const float sc  = (third == 0) ? ATT_SCALE : 1.0f;
#pragma unroll
  for (int ct = 0; ct < 4; ++ct) {
    int n = nmod + ct * 16 + mn;
    int h = n >> 6, d = n & 63;
    float bv = bias[third * 768 + n];
#pragma unroll
    for (int rt = 0; rt < 4; ++rt) {
      int m  = m0 + wr * 64 + rt * 16 + quad * 4;
      int b  = m >> 10, t0 = m & 1023;
      size_t bh = (size_t)b * 12 + h;
      if (third == 2) {
        bf16x4 pk;
#pragma unroll
        for (int r = 0; r < 4; ++r) pk[r] = (bf16)(acc[rt][ct][r] + bv);
        *(bf16x4*)(Vo + (bh * 64 + d) * 1024 + t0) = pk;   // V^T
      } else {
        bf16* dst = (third == 0 ? Qo : Ko) + (bh * 1024 + t0) * 64 + d;
#pragma unroll
        for (int r = 0; r < 4; ++r) dst[(size_t)r * 64] = (bf16)((acc[rt][ct][r] + bv) * sc);
      }
    }
  }
}

// ---------------------------------------------------------------------------
// Attention v9 = v8 (global-direct, barrier-free; L2-residency CONFIRMED by
//   v8 counters: FETCH 23 MB vs 153 MB logical) + register latency hiding.
//   v8 failed on latency: VGPR=76 shows the compiler rematerialized the
//   fragment loads per-ct -> ~16 serial L2 round-trips (~300 cyc) per iter,
//   MfmaUtil 6%. v9 forces a software pipeline in REGISTERS:
//     - K fragments double-buffered (kA/kB), loaded one full iteration
//       ahead (unroll-2 loop, all indices static per rule #20);
//     - V fragments loaded at iter start; first use is after the entire
//       QK+S phase (~400+ cyc cover), scheduler free to hoist (no barriers).
//   Zero cross-wave dependencies remain (S rows wave-private), so waves
//   run fully independently; causal imbalance self-levels.
// ---------------------------------------------------------------------------
__global__ __launch_bounds__(256, 3)
void attn_kernel(const bf16* __restrict__ Q, const bf16* __restrict__ K,
                 const bf16* __restrict__ Vt, float* __restrict__ out) {
  __shared__ __align__(16) char ldsS[16384];   // 128 rows x 128B (A-half, B-half)

  const int tid  = threadIdx.x;
  const int wave = tid >> 6, lane = tid & 63;
  const int quad = lane >> 4, mn = lane & 15;
  const int bh  = blockIdx.x;
  const int qta = blockIdx.y;            // 0..7
  const int qtb = 15 - qta;              // 8..15
  const int qa0 = qta * 64, qb0 = qtb * 64;

  const bf16* Qg  = Q  + (size_t)bh * 65536;
  const bf16* Kg0 = K  + (size_t)bh * 65536;
  const bf16* Vg0 = Vt + (size_t)bh * 65536;

  // Q fragments: lane mn -> row base+mn, d = quad*8.. / 32+quad*8..
  bf16x8 qfA[2], qfB[2];
  {
    const bf16* ra = Qg + (size_t)(qa0 + wave * 16 + mn) * 64;
    qfA[0] = *(const bf16x8*)(ra + quad * 8);
    qfA[1] = *(const bf16x8*)(ra + 32 + quad * 8);
    const bf16* rb = Qg + (size_t)(qb0 + wave * 16 + mn) * 64;
    qfB[0] = *(const bf16x8*)(rb + quad * 8);
    qfB[1] = *(const bf16x8*)(rb + 32 + quad * 8);
  }

  f32x4 yA[4] = {}, yB[4] = {};

  const int srow = (wave * 16 + mn) * 128;   // within a half (half adds 8192)
  const int sw = mn & 7;

  auto loadK = [&](int j, bf16x8 (&kf)[4][2]) {
#pragma unroll
    for (int ct = 0; ct < 4; ++ct) {
      const bf16* kr = Kg0 + (size_t)(j * 64 + ct * 16 + mn) * 64 + quad * 8;
      kf[ct][0] = *(const bf16x8*)(kr);
      kf[ct][1] = *(const bf16x8*)(kr + 32);
    }
  };
  auto loadV = [&](int j, bf16x8 (&vf)[4][2]) {
#pragma unroll
    for (int ct = 0; ct < 4; ++ct) {
      const bf16* vr = Vg0 + (size_t)(ct * 16 + mn) * 1024 + j * 64 + quad * 8;
      vf[ct][0] = *(const bf16x8*)(vr);
      vf[ct][1] = *(const bf16x8*)(vr + 32);
    }
  };

  auto qk_half = [&](int j, const bf16x8 (&kf)[4][2], const bf16x8* qf,
                     int half, int qrow, bool diag) {
    // S^T = K Q^T: lane holds (kk = j*64+ct*16+quad*4+r, q = qrow=base+mn)
#pragma unroll
    for (int ct = 0; ct < 4; ++ct) {
      f32x4 a = {};
      a = __builtin_amdgcn_mfma_f32_16x16x32_bf16(kf[ct][0], qf[0], a, 0, 0, 0);
      a = __builtin_amdgcn_mfma_f32_16x16x32_bf16(kf[ct][1], qf[1], a, 0, 0, 0);
      const int kkg = j * 64 + ct * 16 + quad * 4;
      bf16x4 pk;
#pragma unroll
      for (int r = 0; r < 4; ++r) {
        float v = a[r];
        v = v > 0.f ? v : 0.f;
        if (diag && kkg + r > qrow) v = 0.f;
        pk[r] = (bf16)v;
      }
      *(bf16x4*)(ldsS + half * 8192 + srow +
                 (((ct * 4 + quad) ^ (sw << 1)) & 15) * 8) = pk;
    }
  };
  auto sv_half = [&](const bf16x8 (&vf)[4][2], f32x4* y, int half) {
#pragma unroll
    for (int kb = 0; kb < 2; ++kb) {
      bf16x8 sf = *(const bf16x8*)(ldsS + half * 8192 + srow +
                                   ((kb * 4 + quad) ^ sw) * 16);
#pragma unroll
      for (int ct = 0; ct < 4; ++ct)
        y[ct] = __builtin_amdgcn_mfma_f32_16x16x32_bf16(sf, vf[ct][kb], y[ct], 0, 0, 0);
    }
  };

  auto computeIter = [&](int j, const bf16x8 (&kf)[4][2], const bf16x8 (&vf)[4][2]) {
    if (j <= qta) qk_half(j, kf, qfA, 0, qa0 + wave * 16 + mn, j == qta);
    qk_half(j, kf, qfB, 1, qb0 + wave * 16 + mn, j == qtb);
    if (j <= qta) sv_half(vf, yA, 0);
    sv_half(vf, yB, 1);
  };

  // software pipeline: K fragments one iteration ahead (static buffers)
  bf16x8 kA[4][2], kB[4][2], vf[4][2];
  loadK(0, kA);
  for (int j = 0; j <= qtb; j += 2) {
    if (j + 1 <= qtb) loadK(j + 1, kB);
    loadV(j, vf);
    computeIter(j, kA, vf);
    if (j + 1 <= qtb) {
      if (j + 2 <= qtb) loadK(j + 2, kA);
      loadV(j + 1, vf);
      computeIter(j + 1, kB, vf);
    }
  }

  // write out: out[b][t][h*64+d]; yacc: q = wave*16+quad*4+r, d = ct*16+mn
  const int b = bh / 12, h = bh % 12;
  {
    float* ob = out + ((size_t)b * 1024 + qa0 + wave * 16 + quad * 4) * 768 + h * 64;
#pragma unroll
    for (int ct = 0; ct < 4; ++ct)
#pragma unroll
      for (int r = 0; r < 4; ++r)
        ob[(size_t)r * 768 + ct * 16 + mn] = yA[ct][r];
  }
  {
    float* ob = out + ((size_t)b * 1024 + qb0 + wave * 16 + quad * 4) * 768 + h * 64;
#pragma unroll
    for (int ct = 0; ct < 4; ++ct)
#pragma unroll
      for (int r = 0; r < 4; ++r)
        ob[(size_t)r * 768 + ct * 16 + mn] = yB[ct][r];
  }
}

// ---------------------------------------------------------------------------
extern "C" void kernel_launch(void* const* d_in, const int* in_sizes, int n_in,
                              void* d_out, int out_size, void* d_ws, size_t ws_size,
                              hipStream_t stream) {
  const float* x    = (const float*)d_in[0];   // [8,1024,768]
  const float* W    = (const float*)d_in[1];   // [768,2304]
  const float* bias = (const float*)d_in[2];   // [2304]
  float* out = (float*)d_out;                  // [8,1024,768]

  char* ws = (char*)d_ws;
  bf16* xb = (bf16*)(ws);                      // 8192*768
  bf16* Wt = (bf16*)(ws + 12582912);           // 2304*768
  bf16* Qb = (bf16*)(ws + 16121856);           // 96*1024*64
  bf16* Kb = (bf16*)(ws + 28704768);           // 96*1024*64
  bf16* Vb = (bf16*)(ws + 41287680);           // 96*64*1024 (V^T)

  prep_kernel<<<4800, 256, 0, stream>>>(x, xb, W, Wt);
  qkv_gemm_kernel<<<dim3(18, 64), 256, 0, stream>>>(xb, Wt, bias, Qb, Kb, Vb);
  attn_kernel<<<dim3(96, 8), 256, 0, stream>>>(Qb, Kb, Vb, out);
}

// Round 9
// 160.782 us; speedup vs baseline: 1.3426x; 1.3426x over previous
//
#include <hip/hip_runtime.h>
#include <stdint.h>

typedef __bf16 bf16;
typedef __attribute__((ext_vector_type(8))) __bf16 bf16x8;
typedef __attribute__((ext_vector_type(4))) __bf16 bf16x4;
typedef __attribute__((ext_vector_type(4))) float  f32x4;

#define ATT_SCALE 0.125f   // 1/sqrt(64), folded into Q at GEMM epilogue

// ---------------------------------------------------------------------------
// async 16B global -> LDS (wave-uniform LDS base + lane*16, per-lane gaddr)
// ---------------------------------------------------------------------------
__device__ __forceinline__ void async16(void* lds, const void* g) {
  __builtin_amdgcn_global_load_lds(
      (__attribute__((address_space(1))) void*)(void*)g,
      (__attribute__((address_space(3))) void*)lds,
      16, 0, 0);
}

// ---------------------------------------------------------------------------
// Fused prep: blocks [0,3072) convert x fp32->bf16 (8 elems/thread);
//             blocks [3072,4800) transpose W [768x2304] fp32 -> Wt bf16.
// ---------------------------------------------------------------------------
__global__ void prep_kernel(const float* __restrict__ x, bf16* __restrict__ y,
                            const float* __restrict__ W, bf16* __restrict__ Wt) {
  __shared__ float tile[32][33];
  const int tid = threadIdx.x;
  if (blockIdx.x < 3072) {
    size_t i = ((size_t)blockIdx.x * 256 + tid) * 8;
    float4 a = *(const float4*)(x + i);
    float4 b = *(const float4*)(x + i + 4);
    bf16x8 o;
    o[0] = (bf16)a.x; o[1] = (bf16)a.y; o[2] = (bf16)a.z; o[3] = (bf16)a.w;
    o[4] = (bf16)b.x; o[5] = (bf16)b.y; o[6] = (bf16)b.z; o[7] = (bf16)b.w;
    *(bf16x8*)(y + i) = o;
  } else {
    const int bid = blockIdx.x - 3072;        // 0..1727
    const int tx = tid & 31, ty = tid >> 5;   // 32 x 8
    const int n0 = (bid % 72) * 32, k0 = (bid / 72) * 32;
#pragma unroll
    for (int r = 0; r < 4; ++r)
      tile[ty + r * 8][tx] = W[(size_t)(k0 + ty + r * 8) * 2304 + n0 + tx];
    __syncthreads();
#pragma unroll
    for (int r = 0; r < 4; ++r)
      Wt[(size_t)(n0 + ty + r * 8) * 768 + k0 + tx] = (bf16)tile[tx][ty + r * 8];
  }
}

// ---------------------------------------------------------------------------
// QKV GEMM v3 (unchanged from R6, 42.3 us steady): 128x128 tile, BK=64,
//   XCD swizzle (FETCH 70->48 MB), counted-vmcnt two-barrier K-loop.
// ---------------------------------------------------------------------------
__global__ void qkv_gemm_kernel(const bf16* __restrict__ A, const bf16* __restrict__ Bw,
                                const float* __restrict__ bias,
                                bf16* __restrict__ Qo, bf16* __restrict__ Ko,
                                bf16* __restrict__ Vo) {
  __shared__ __align__(16) char lds[65536];   // 2 x (A 16KB + B 16KB)

  const int tid  = threadIdx.x;
  const int wave = tid >> 6, lane = tid & 63;
  const int quad = lane >> 4, mn = lane & 15;
  const int wr = wave >> 1, wc = wave & 1;

  // XCD swizzle: orig dispatch id -> contiguous per-XCD chunk (144 blocks)
  const int orig = blockIdx.y * 18 + blockIdx.x;   // hw flat id (x fastest)
  const int swz  = (orig & 7) * 144 + (orig >> 3); // 1152 = 8 * 144, bijective
  const int m0 = (swz / 18) * 128;
  const int n0 = (swz % 18) * 128;

  f32x4 acc[4][4] = {};

  const int lrow = lane >> 3;           // 0..7  (row within 8-row group)
  const int cg   = (lane & 7) ^ lrow;   // global 16B-chunk index (swizzled)

  auto stage = [&](int kt, char* buf) {
    char* Al = buf;
    char* Bl = buf + 16384;
#pragma unroll
    for (int u = 0; u < 4; ++u) {
      const int t   = wave * 4 + u;      // 8-row group 0..15
      const int row = t * 8 + lrow;      // tile row 0..127
      async16(Al + t * 1024 + lane * 16,
              A  + (size_t)(m0 + row) * 768 + kt + cg * 8);
      async16(Bl + t * 1024 + lane * 16,
              Bw + (size_t)(n0 + row) * 768 + kt + cg * 8);
    }
  };

#define SCHED0() __builtin_amdgcn_sched_barrier(0)

  stage(0, lds); SCHED0();

  for (int j = 0; j < 12; ++j) {
    // BAR-A: all waves finished iter j-1 LDS reads (WAR gate for buf (j+1)&1)
    asm volatile("s_waitcnt lgkmcnt(0)" ::: "memory"); SCHED0();
    __builtin_amdgcn_s_barrier(); SCHED0();
    if (j < 11) { stage((j + 1) * 64, lds + ((j + 1) & 1) * 32768); SCHED0(); }
    // complete own stage j (8 loads); leave stage j+1 in flight
    if (j < 11) { asm volatile("s_waitcnt vmcnt(8)" ::: "memory"); }
    else        { asm volatile("s_waitcnt vmcnt(0)" ::: "memory"); }
    SCHED0();
    __builtin_amdgcn_s_barrier(); SCHED0();   // BAR-B: publish stage j

    char* Al = lds + (j & 1) * 32768;
    char* Bl = Al + 16384;

#pragma unroll
    for (int s = 0; s < 2; ++s) {        // two K=32 steps within BK=64
      bf16x8 af[4], bfr[4];
      const int csw = ((s * 4 + quad) ^ (mn & 7)) * 16;  // swizzled chunk offset
#pragma unroll
      for (int i = 0; i < 4; ++i) {
        af[i]  = *(const bf16x8*)(Al + (wr * 64 + i * 16 + mn) * 128 + csw);
        bfr[i] = *(const bf16x8*)(Bl + (wc * 64 + i * 16 + mn) * 128 + csw);
      }
#pragma unroll
      for (int i = 0; i < 4; ++i)
#pragma unroll
        for (int jj = 0; jj < 4; ++jj)
          acc[i][jj] = __builtin_amdgcn_mfma_f32_16x16x32_bf16(af[i], bfr[jj], acc[i][jj], 0, 0, 0);
    }
  }

#undef SCHED0

  // epilogue
  const int ng    = n0 + wc * 64;
  const int third = ng / 768;           // 0=Q 1=K 2=V
  const int nmod  = ng % 768;
  const float sc  = (third == 0) ? ATT_SCALE : 1.0f;
#pragma unroll
  for (int ct = 0; ct < 4; ++ct) {
    int n = nmod + ct * 16 + mn;
    int h = n >> 6, d = n & 63;
    float bv = bias[third * 768 + n];
#pragma unroll
    for (int rt = 0; rt < 4; ++rt) {
      int m  = m0 + wr * 64 + rt * 16 + quad * 4;
      int b  = m >> 10, t0 = m & 1023;
      size_t bh = (size_t)b * 12 + h;
      if (third == 2) {
        bf16x4 pk;
#pragma unroll
        for (int r = 0; r < 4; ++r) pk[r] = (bf16)(acc[rt][ct][r] + bv);
        *(bf16x4*)(Vo + (bh * 64 + d) * 1024 + t0) = pk;   // V^T
      } else {
        bf16* dst = (third == 0 ? Qo : Ko) + (bh * 1024 + t0) * 64 + d;
#pragma unroll
        for (int r = 0; r < 4; ++r) dst[(size_t)r * 64] = (bf16)((acc[rt][ct][r] + bv) * sc);
      }
    }
  }
}

// ---------------------------------------------------------------------------
// Attention v10 = v7 skeleton (K LDS-staged, counted vmcnt, two barriers)
//   with V read DIRECT from global into registers (guide m169 hybrid):
//   - v7 measured ~45us: staging pipeline sound but 28 LDS ops/iter/wave.
//   - v8/v9 (all-global) proved K/V are L2-resident (FETCH 23 MB) but raw
//     L2 latency unpipelined (v8, MfmaUtil 6%) or scratch-spilled (v9,
//     WRITE_SIZE 114 MB) kills it.
//   - V's first use is AFTER the whole QK+S phase (~400+ cyc cover), so
//     global->VGPR V loads issued at iter start are latency-hidden; K is
//     needed immediately -> stays LDS-staged. vf declared inside the loop
//     body (v8-style, no cross-iter arrays) -> no scratch.
//   vmcnt bookkeeping (issue order pinned V < K-DMA via sched_barrier):
//     at the wait, outstanding = K(j)[2] + V(j)[8] + K(j+1)[2] = 12
//     -> vmcnt(10) completes exactly K(j); last iter (no K(j+1)): vmcnt(8).
//     V completion is enforced by compiler-inserted waits at SV (VGPR deps).
//   LDS = K dbuf 16KB + S 16KB = 32KB.
// ---------------------------------------------------------------------------
__global__ __launch_bounds__(256, 3)
void attn_kernel(const bf16* __restrict__ Q, const bf16* __restrict__ K,
                 const bf16* __restrict__ Vt, float* __restrict__ out) {
  __shared__ __align__(16) char lds[32768];
  // K buf c at lds + c*8192 (c = j&1): 64 rows x 128B (XOR-swizzled)
  char* ldsS = lds + 16384;              // 128 rows x 128B (A-half, B-half)

  const int tid  = threadIdx.x;
  const int wave = tid >> 6, lane = tid & 63;
  const int quad = lane >> 4, mn = lane & 15;
  const int bh  = blockIdx.x;
  const int qta = blockIdx.y;            // 0..7
  const int qtb = 15 - qta;              // 8..15
  const int qa0 = qta * 64, qb0 = qtb * 64;

  const bf16* Qg  = Q  + (size_t)bh * 65536;
  const bf16* Kg0 = K  + (size_t)bh * 65536;
  const bf16* Vg0 = Vt + (size_t)bh * 65536;

#define SCHED0() __builtin_amdgcn_sched_barrier(0)

  // Q fragments: lane mn -> row base+mn, d = quad*8.. / 32+quad*8..
  bf16x8 qfA[2], qfB[2];
  {
    const bf16* ra = Qg + (size_t)(qa0 + wave * 16 + mn) * 64;
    qfA[0] = *(const bf16x8*)(ra + quad * 8);
    qfA[1] = *(const bf16x8*)(ra + 32 + quad * 8);
    const bf16* rb = Qg + (size_t)(qb0 + wave * 16 + mn) * 64;
    qfB[0] = *(const bf16x8*)(rb + quad * 8);
    qfB[1] = *(const bf16x8*)(rb + 32 + quad * 8);
  }
  SCHED0();   // Q-loads retire before the loop's counted waits matter

  f32x4 yA[4] = {}, yB[4] = {};

  const int lrow = lane >> 3;            // 0..7
  const int cg   = (lane & 7) ^ lrow;    // swizzled global chunk

  auto stageK = [&](int j, char* buf) {
#pragma unroll
    for (int u2 = 0; u2 < 2; ++u2) {
      const int u   = wave * 2 + u2;     // 8-row group 0..7
      const int row = u * 8 + lrow;      // 0..63
      async16(buf + u * 1024 + lane * 16,
              Kg0 + (size_t)(j * 64 + row) * 64 + cg * 8);
    }
  };

  const int srow = (wave * 16 + mn) * 128;   // within a half (half adds 8192)
  const int sw = mn & 7;

  // prologue: stage K tile 0 (2 DMA); drain so iter-0 vmcnt arithmetic is
  // clean regardless of Q-load retirement (order-independent, one-time)
  stageK(0, lds); SCHED0();

  for (int j = 0; j <= qtb; ++j) {
    // drain own LDS ops, then BAR-A: all waves finished iter j-1 reads
    asm volatile("s_waitcnt lgkmcnt(0)" ::: "memory"); SCHED0();
    __builtin_amdgcn_s_barrier(); SCHED0();

    // V(j) direct global->VGPR (L2-resident); first use is after QK+S phase
    bf16x8 vf[4][2];
#pragma unroll
    for (int ct = 0; ct < 4; ++ct) {
      const bf16* vr = Vg0 + (size_t)(ct * 16 + mn) * 1024 + j * 64 + quad * 8;
      vf[ct][0] = *(const bf16x8*)(vr);
      vf[ct][1] = *(const bf16x8*)(vr + 32);
    }
    SCHED0();
    if (j < qtb) { stageK(j + 1, lds + ((j + 1) & 1) * 8192); SCHED0(); }
    // complete K(j): outstanding = K(j) 2 + V(j) 8 + K(j+1) 2 -> vmcnt(10)
    if (j < qtb) { asm volatile("s_waitcnt vmcnt(10)" ::: "memory"); }
    else         { asm volatile("s_waitcnt vmcnt(8)"  ::: "memory"); }
    SCHED0();
    __builtin_amdgcn_s_barrier(); SCHED0();   // BAR-B: publish K(j)

    char* bK = lds + (j & 1) * 8192;

    // K fragments from LDS (conflict-free swizzled reads)
    bf16x8 kf[4][2];
#pragma unroll
    for (int ct = 0; ct < 4; ++ct) {
      const int ro = (ct * 16 + mn) * 128;
      kf[ct][0] = *(const bf16x8*)(bK + ro + ((quad)     ^ sw) * 16);
      kf[ct][1] = *(const bf16x8*)(bK + ro + ((4 + quad) ^ sw) * 16);
    }

    auto qk_half = [&](const bf16x8* qf, int half, int qrow, bool diag) {
      // S^T = K Q^T: lane holds (kk = j*64+ct*16+quad*4+r, q = qrow=base+mn)
#pragma unroll
      for (int ct = 0; ct < 4; ++ct) {
        f32x4 a = {};
        a = __builtin_amdgcn_mfma_f32_16x16x32_bf16(kf[ct][0], qf[0], a, 0, 0, 0);
        a = __builtin_amdgcn_mfma_f32_16x16x32_bf16(kf[ct][1], qf[1], a, 0, 0, 0);
        const int kkg = j * 64 + ct * 16 + quad * 4;
        bf16x4 pk;
#pragma unroll
        for (int r = 0; r < 4; ++r) {
          float v = a[r];
          v = v > 0.f ? v : 0.f;
          if (diag && kkg + r > qrow) v = 0.f;
          pk[r] = (bf16)v;
        }
        *(bf16x4*)(ldsS + half * 8192 + srow +
                   (((ct * 4 + quad) ^ (sw << 1)) & 15) * 8) = pk;
      }
    };
    auto sv_half = [&](f32x4* y, int half) {
#pragma unroll
      for (int kb = 0; kb < 2; ++kb) {
        bf16x8 sf = *(const bf16x8*)(ldsS + half * 8192 + srow +
                                     ((kb * 4 + quad) ^ sw) * 16);
#pragma unroll
        for (int ct = 0; ct < 4; ++ct)
          y[ct] = __builtin_amdgcn_mfma_f32_16x16x32_bf16(sf, vf[ct][kb], y[ct], 0, 0, 0);
      }
    };

    if (j <= qta) qk_half(qfA, 0, qa0 + wave * 16 + mn, j == qta);
    qk_half(qfB, 1, qb0 + wave * 16 + mn, j == qtb);
    if (j <= qta) sv_half(yA, 0);
    sv_half(yB, 1);
  }

#undef SCHED0

  // write out: out[b][t][h*64+d]; yacc: q = wave*16+quad*4+r, d = ct*16+mn
  const int b = bh / 12, h = bh % 12;
  {
    float* ob = out + ((size_t)b * 1024 + qa0 + wave * 16 + quad * 4) * 768 + h * 64;
#pragma unroll
    for (int ct = 0; ct < 4; ++ct)
#pragma unroll
      for (int r = 0; r < 4; ++r)
        ob[(size_t)r * 768 + ct * 16 + mn] = yA[ct][r];
  }
  {
    float* ob = out + ((size_t)b * 1024 + qb0 + wave * 16 + quad * 4) * 768 + h * 64;
#pragma unroll
    for (int ct = 0; ct < 4; ++ct)
#pragma unroll
      for (int r = 0; r < 4; ++r)
        ob[(size_t)r * 768 + ct * 16 + mn] = yB[ct][r];
  }
}

// ---------------------------------------------------------------------------
extern "C" void kernel_launch(void* const* d_in, const int* in_sizes, int n_in,
                              void* d_out, int out_size, void* d_ws, size_t ws_size,
                              hipStream_t stream) {
  const float* x    = (const float*)d_in[0];   // [8,1024,768]
  const float* W    = (const float*)d_in[1];   // [768,2304]
  const float* bias = (const float*)d_in[2];   // [2304]
  float* out = (float*)d_out;                  // [8,1024,768]

  char* ws = (char*)d_ws;
  bf16* xb = (bf16*)(ws);                      // 8192*768
  bf16* Wt = (bf16*)(ws + 12582912);           // 2304*768
  bf16* Qb = (bf16*)(ws + 16121856);           // 96*1024*64
  bf16* Kb = (bf16*)(ws + 28704768);           // 96*1024*64
  bf16* Vb = (bf16*)(ws + 41287680);           // 96*64*1024 (V^T)

  prep_kernel<<<4800, 256, 0, stream>>>(x, xb, W, Wt);
  qkv_gemm_kernel<<<dim3(18, 64), 256, 0, stream>>>(xb, Wt, bias, Qb, Kb, Vb);
  attn_kernel<<<dim3(96, 8), 256, 0, stream>>>(Qb, Kb, Vb, out);
}

// Round 12
// 146.570 us; speedup vs baseline: 1.4728x; 1.0970x over previous
//
#include <hip/hip_runtime.h>
#include <stdint.h>

typedef __bf16 bf16;
typedef __attribute__((ext_vector_type(8))) __bf16 bf16x8;
typedef __attribute__((ext_vector_type(4))) __bf16 bf16x4;
typedef __attribute__((ext_vector_type(4))) float  f32x4;

#define ATT_SCALE 0.125f   // 1/sqrt(64), folded into Q at GEMM epilogue

// ---------------------------------------------------------------------------
// async 16B global -> LDS (wave-uniform LDS base + lane*16, per-lane gaddr)
// ---------------------------------------------------------------------------
__device__ __forceinline__ void async16(void* lds, const void* g) {
  __builtin_amdgcn_global_load_lds(
      (__attribute__((address_space(1))) void*)(void*)g,
      (__attribute__((address_space(3))) void*)lds,
      16, 0, 0);
}

// ---------------------------------------------------------------------------
// Fused prep: blocks [0,3072) convert x fp32->bf16 (8 elems/thread);
//             blocks [3072,4800) transpose W [768x2304] fp32 -> Wt bf16.
// ---------------------------------------------------------------------------
__global__ void prep_kernel(const float* __restrict__ x, bf16* __restrict__ y,
                            const float* __restrict__ W, bf16* __restrict__ Wt) {
  __shared__ float tile[32][33];
  const int tid = threadIdx.x;
  if (blockIdx.x < 3072) {
    size_t i = ((size_t)blockIdx.x * 256 + tid) * 8;
    float4 a = *(const float4*)(x + i);
    float4 b = *(const float4*)(x + i + 4);
    bf16x8 o;
    o[0] = (bf16)a.x; o[1] = (bf16)a.y; o[2] = (bf16)a.z; o[3] = (bf16)a.w;
    o[4] = (bf16)b.x; o[5] = (bf16)b.y; o[6] = (bf16)b.z; o[7] = (bf16)b.w;
    *(bf16x8*)(y + i) = o;
  } else {
    const int bid = blockIdx.x - 3072;        // 0..1727
    const int tx = tid & 31, ty = tid >> 5;   // 32 x 8
    const int n0 = (bid % 72) * 32, k0 = (bid / 72) * 32;
#pragma unroll
    for (int r = 0; r < 4; ++r)
      tile[ty + r * 8][tx] = W[(size_t)(k0 + ty + r * 8) * 2304 + n0 + tx];
    __syncthreads();
#pragma unroll
    for (int r = 0; r < 4; ++r)
      Wt[(size_t)(n0 + ty + r * 8) * 768 + k0 + tx] = (bf16)tile[tx][ty + r * 8];
  }
}

// ---------------------------------------------------------------------------
// QKV GEMM v3 (unchanged from R6, 42.3 us steady): 128x128 tile, BK=64,
//   XCD swizzle (FETCH 70->48 MB), counted-vmcnt two-barrier K-loop.
// ---------------------------------------------------------------------------
__global__ void qkv_gemm_kernel(const bf16* __restrict__ A, const bf16* __restrict__ Bw,
                                const float* __restrict__ bias,
                                bf16* __restrict__ Qo, bf16* __restrict__ Ko,
                                bf16* __restrict__ Vo) {
  __shared__ __align__(16) char lds[65536];   // 2 x (A 16KB + B 16KB)

  const int tid  = threadIdx.x;
  const int wave = tid >> 6, lane = tid & 63;
  const int quad = lane >> 4, mn = lane & 15;
  const int wr = wave >> 1, wc = wave & 1;

  // XCD swizzle: orig dispatch id -> contiguous per-XCD chunk (144 blocks)
  const int orig = blockIdx.y * 18 + blockIdx.x;   // hw flat id (x fastest)
  const int swz  = (orig & 7) * 144 + (orig >> 3); // 1152 = 8 * 144, bijective
  const int m0 = (swz / 18) * 128;
  const int n0 = (swz % 18) * 128;

  f32x4 acc[4][4] = {};

  const int lrow = lane >> 3;           // 0..7  (row within 8-row group)
  const int cg   = (lane & 7) ^ lrow;   // global 16B-chunk index (swizzled)

  auto stage = [&](int kt, char* buf) {
    char* Al = buf;
    char* Bl = buf + 16384;
#pragma unroll
    for (int u = 0; u < 4; ++u) {
      const int t   = wave * 4 + u;      // 8-row group 0..15
      const int row = t * 8 + lrow;      // tile row 0..127
      async16(Al + t * 1024 + lane * 16,
              A  + (size_t)(m0 + row) * 768 + kt + cg * 8);
      async16(Bl + t * 1024 + lane * 16,
              Bw + (size_t)(n0 + row) * 768 + kt + cg * 8);
    }
  };

#define SCHED0() __builtin_amdgcn_sched_barrier(0)

  stage(0, lds); SCHED0();

  for (int j = 0; j < 12; ++j) {
    // BAR-A: all waves finished iter j-1 LDS reads (WAR gate for buf (j+1)&1)
    asm volatile("s_waitcnt lgkmcnt(0)" ::: "memory"); SCHED0();
    __builtin_amdgcn_s_barrier(); SCHED0();
    if (j < 11) { stage((j + 1) * 64, lds + ((j + 1) & 1) * 32768); SCHED0(); }
    // complete own stage j (8 loads); leave stage j+1 in flight
    if (j < 11) { asm volatile("s_waitcnt vmcnt(8)" ::: "memory"); }
    else        { asm volatile("s_waitcnt vmcnt(0)" ::: "memory"); }
    SCHED0();
    __builtin_amdgcn_s_barrier(); SCHED0();   // BAR-B: publish stage j

    char* Al = lds + (j & 1) * 32768;
    char* Bl = Al + 16384;

#pragma unroll
    for (int s = 0; s < 2; ++s) {        // two K=32 steps within BK=64
      bf16x8 af[4], bfr[4];
      const int csw = ((s * 4 + quad) ^ (mn & 7)) * 16;  // swizzled chunk offset
#pragma unroll
      for (int i = 0; i < 4; ++i) {
        af[i]  = *(const bf16x8*)(Al + (wr * 64 + i * 16 + mn) * 128 + csw);
        bfr[i] = *(const bf16x8*)(Bl + (wc * 64 + i * 16 + mn) * 128 + csw);
      }
#pragma unroll
      for (int i = 0; i < 4; ++i)
#pragma unroll
        for (int jj = 0; jj < 4; ++jj)
          acc[i][jj] = __builtin_amdgcn_mfma_f32_16x16x32_bf16(af[i], bfr[jj], acc[i][jj], 0, 0, 0);
    }
  }

#undef SCHED0

  // epilogue
  const int ng    = n0 + wc * 64;
  const int third = ng / 768;           // 0=Q 1=K 2=V
  const int nmod  = ng % 768;
  const float sc  = (third == 0) ? ATT_SCALE : 1.0f;
#pragma unroll
  for (int ct = 0; ct < 4; ++ct) {
    int n = nmod + ct * 16 + mn;
    int h = n >> 6, d = n & 63;
    float bv = bias[third * 768 + n];
#pragma unroll
    for (int rt = 0; rt < 4; ++rt) {
      int m  = m0 + wr * 64 + rt * 16 + quad * 4;
      int b  = m >> 10, t0 = m & 1023;
      size_t bh = (size_t)b * 12 + h;
      if (third == 2) {
        bf16x4 pk;
#pragma unroll
        for (int r = 0; r < 4; ++r) pk[r] = (bf16)(acc[rt][ct][r] + bv);
        *(bf16x4*)(Vo + (bh * 64 + d) * 1024 + t0) = pk;   // V^T
      } else {
        bf16* dst = (third == 0 ? Qo : Ko) + (bh * 1024 + t0) * 64 + d;
#pragma unroll
        for (int r = 0; r < 4; ++r) dst[(size_t)r * 64] = (bf16)((acc[rt][ct][r] + bv) * sc);
      }
    }
  }
}

// ---------------------------------------------------------------------------
// Attention v11 = v7 VERBATIM (best measured structure: K+V DMA-staged,
//   counted vmcnt, double-buffer, 48KB LDS, 3 blocks/CU) + XCD swizzle.
//   Three-point evidence closed the dataflow question: v7 (DMA both) ~40us,
//   v10 (V per-lane L2 loads) 50.5us, v8 (all per-lane) 81us -> DMA staging
//   wins at this shape (no VGPR cost, ~30cyc LDS consume vs ~300cyc L2).
//   New: bijective XCD remap (768 = 8 x 96 exact). Default dispatch puts
//   the 8 blocks sharing one bh's K/V (256KB) on 8 different XCDs and each
//   XCD touches all 96 bh. Remap: XCD k <- bh in [12k,12k+12) x all y;
//   per-XCD K/V working set 3MB < 4MB L2; all 96 blocks of an XCD
//   co-resident (3/CU x 32 CU).
//   (R10/R11 runs were infrastructure failures — container died before
//   compile both times; resubmitted unchanged for measurement.)
// ---------------------------------------------------------------------------
__global__ __launch_bounds__(256, 3)
void attn_kernel(const bf16* __restrict__ Q, const bf16* __restrict__ K,
                 const bf16* __restrict__ Vt, float* __restrict__ out) {
  __shared__ __align__(16) char lds[49152];
  // buf c at lds + c*16384 (c = j&1): K 64x128B then V 64x128B (XOR-swizzled)
  char* ldsS = lds + 32768;              // 128 rows x 128B (A-half, B-half)

  const int tid  = threadIdx.x;
  const int wave = tid >> 6, lane = tid & 63;
  const int quad = lane >> 4, mn = lane & 15;

  // XCD-aware remap (hw flat id: x fastest). k = XCD under round-robin.
  const int orig = blockIdx.y * 96 + blockIdx.x;   // [0,768)
  const int k8   = orig & 7;                       // XCD chunk
  const int r96  = orig >> 3;                      // [0,96)
  const int bh   = k8 * 12 + (r96 % 12);           // 12 contiguous bh per XCD
  const int qta  = r96 / 12;                       // 0..7
  const int qtb = 15 - qta;              // 8..15
  const int qa0 = qta * 64, qb0 = qtb * 64;

  const bf16* Qg  = Q  + (size_t)bh * 65536;
  const bf16* Kg0 = K  + (size_t)bh * 65536;
  const bf16* Vg0 = Vt + (size_t)bh * 65536;

#define SCHED0() __builtin_amdgcn_sched_barrier(0)

  // Q fragments: lane mn -> row base+mn, d = quad*8.. / 32+quad*8..
  bf16x8 qfA[2], qfB[2];
  {
    const bf16* ra = Qg + (size_t)(qa0 + wave * 16 + mn) * 64;
    qfA[0] = *(const bf16x8*)(ra + quad * 8);
    qfA[1] = *(const bf16x8*)(ra + 32 + quad * 8);
    const bf16* rb = Qg + (size_t)(qb0 + wave * 16 + mn) * 64;
    qfB[0] = *(const bf16x8*)(rb + quad * 8);
    qfB[1] = *(const bf16x8*)(rb + 32 + quad * 8);
  }
  SCHED0();   // pin Q-loads before the staged DMA (vmcnt order discipline)

  f32x4 yA[4] = {}, yB[4] = {};

  const int lrow = lane >> 3;            // 0..7
  const int cg   = (lane & 7) ^ lrow;    // swizzled global chunk

  auto stageKV = [&](int j, char* buf) {
#pragma unroll
    for (int u2 = 0; u2 < 2; ++u2) {
      const int u   = wave * 2 + u2;     // 8-row group 0..7
      const int row = u * 8 + lrow;      // 0..63
      async16(buf + u * 1024 + lane * 16,
              Kg0 + (size_t)(j * 64 + row) * 64 + cg * 8);
      async16(buf + 8192 + u * 1024 + lane * 16,
              Vg0 + (size_t)row * 1024 + j * 64 + cg * 8);
    }
  };

  const int srow = (wave * 16 + mn) * 128;   // within a half (half adds 8192)

  // prologue: stage tile 0 only (stage 1 issued inside iter 0 after BAR-A)
  stageKV(0, lds);  SCHED0();

  for (int j = 0; j <= qtb; ++j) {
    // drain own ds ops, then BAR-A: all waves finished iter j-1 LDS reads
    asm volatile("s_waitcnt lgkmcnt(0)" ::: "memory"); SCHED0();
    __builtin_amdgcn_s_barrier(); SCHED0();
    if (j < qtb) { stageKV(j + 1, lds + ((j + 1) & 1) * 16384); SCHED0(); }
    // complete own stage j (leave stage j+1 in flight), then publish
    if (j < qtb) { asm volatile("s_waitcnt vmcnt(4)" ::: "memory"); }
    else         { asm volatile("s_waitcnt vmcnt(0)" ::: "memory"); }
    SCHED0();
    __builtin_amdgcn_s_barrier(); SCHED0();

    char* bK = lds + (j & 1) * 16384;
    char* bV = bK + 8192;

    // hoisted K/V fragments (shared by both halves)
    bf16x8 kf[4][2], vf[4][2];
    const int sw = mn & 7;
#pragma unroll
    for (int ct = 0; ct < 4; ++ct) {
      const int ro = (ct * 16 + mn) * 128;
      kf[ct][0] = *(const bf16x8*)(bK + ro + ((quad)     ^ sw) * 16);
      kf[ct][1] = *(const bf16x8*)(bK + ro + ((4 + quad) ^ sw) * 16);
      vf[ct][0] = *(const bf16x8*)(bV + ro + ((quad)     ^ sw) * 16);
      vf[ct][1] = *(const bf16x8*)(bV + ro + ((4 + quad) ^ sw) * 16);
    }

    auto qk_half = [&](const bf16x8* qf, int half, int qrow, bool diag) {
      // S^T = K Q^T: lane holds (kk = j*64+ct*16+quad*4+r, q = qrow=base+mn)
#pragma unroll
      for (int ct = 0; ct < 4; ++ct) {
        f32x4 a = {};
        a = __builtin_amdgcn_mfma_f32_16x16x32_bf16(kf[ct][0], qf[0], a, 0, 0, 0);
        a = __builtin_amdgcn_mfma_f32_16x16x32_bf16(kf[ct][1], qf[1], a, 0, 0, 0);
        const int kkg = j * 64 + ct * 16 + quad * 4;
        bf16x4 pk;
#pragma unroll
        for (int r = 0; r < 4; ++r) {
          float v = a[r];
          v = v > 0.f ? v : 0.f;
          if (diag && kkg + r > qrow) v = 0.f;
          pk[r] = (bf16)v;
        }
        *(bf16x4*)(ldsS + half * 8192 + srow +
                   (((ct * 4 + quad) ^ (sw << 1)) & 15) * 8) = pk;
      }
    };
    auto sv_half = [&](f32x4* y, int half) {
#pragma unroll
      for (int kb = 0; kb < 2; ++kb) {
        bf16x8 sf = *(const bf16x8*)(ldsS + half * 8192 + srow +
                                     ((kb * 4 + quad) ^ sw) * 16);
#pragma unroll
        for (int ct = 0; ct < 4; ++ct)
          y[ct] = __builtin_amdgcn_mfma_f32_16x16x32_bf16(sf, vf[ct][kb], y[ct], 0, 0, 0);
      }
    };

    if (j <= qta) qk_half(qfA, 0, qa0 + wave * 16 + mn, j == qta);
    qk_half(qfB, 1, qb0 + wave * 16 + mn, j == qtb);
    if (j <= qta) sv_half(yA, 0);
    sv_half(yB, 1);
  }

#undef SCHED0

  // write out: out[b][t][h*64+d]; yacc: q = wave*16+quad*4+r, d = ct*16+mn
  const int b = bh / 12, h = bh % 12;
  {
    float* ob = out + ((size_t)b * 1024 + qa0 + wave * 16 + quad * 4) * 768 + h * 64;
#pragma unroll
    for (int ct = 0; ct < 4; ++ct)
#pragma unroll
      for (int r = 0; r < 4; ++r)
        ob[(size_t)r * 768 + ct * 16 + mn] = yA[ct][r];
  }
  {
    float* ob = out + ((size_t)b * 1024 + qb0 + wave * 16 + quad * 4) * 768 + h * 64;
#pragma unroll
    for (int ct = 0; ct < 4; ++ct)
#pragma unroll
      for (int r = 0; r < 4; ++r)
        ob[(size_t)r * 768 + ct * 16 + mn] = yB[ct][r];
  }
}

// ---------------------------------------------------------------------------
extern "C" void kernel_launch(void* const* d_in, const int* in_sizes, int n_in,
                              void* d_out, int out_size, void* d_ws, size_t ws_size,
                              hipStream_t stream) {
  const float* x    = (const float*)d_in[0];   // [8,1024,768]
  const float* W    = (const float*)d_in[1];   // [768,2304]
  const float* bias = (const float*)d_in[2];   // [2304]
  float* out = (float*)d_out;                  // [8,1024,768]

  char* ws = (char*)d_ws;
  bf16* xb = (bf16*)(ws);                      // 8192*768
  bf16* Wt = (bf16*)(ws + 12582912);           // 2304*768
  bf16* Qb = (bf16*)(ws + 16121856);           // 96*1024*64
  bf16* Kb = (bf16*)(ws + 28704768);           // 96*1024*64
  bf16* Vb = (bf16*)(ws + 41287680);           // 96*64*1024 (V^T)

  prep_kernel<<<4800, 256, 0, stream>>>(x, xb, W, Wt);
  qkv_gemm_kernel<<<dim3(18, 64), 256, 0, stream>>>(xb, Wt, bias, Qb, Kb, Vb);
  attn_kernel<<<dim3(96, 8), 256, 0, stream>>>(Qb, Kb, Vb, out);
}

// Round 13
// 142.140 us; speedup vs baseline: 1.5187x; 1.0312x over previous
//
#include <hip/hip_runtime.h>
#include <stdint.h>

typedef __bf16 bf16;
typedef __attribute__((ext_vector_type(8))) __bf16 bf16x8;
typedef __attribute__((ext_vector_type(4))) __bf16 bf16x4;
typedef __attribute__((ext_vector_type(4))) float  f32x4;

#define ATT_SCALE 0.125f   // 1/sqrt(64), folded into Q at GEMM epilogue

// ---------------------------------------------------------------------------
// async 16B global -> LDS (wave-uniform LDS base + lane*16, per-lane gaddr)
// ---------------------------------------------------------------------------
__device__ __forceinline__ void async16(void* lds, const void* g) {
  __builtin_amdgcn_global_load_lds(
      (__attribute__((address_space(1))) void*)(void*)g,
      (__attribute__((address_space(3))) void*)lds,
      16, 0, 0);
}

// ---------------------------------------------------------------------------
// Fused prep: blocks [0,3072) convert x fp32->bf16 (8 elems/thread);
//             blocks [3072,4800) transpose W [768x2304] fp32 -> Wt bf16.
// ---------------------------------------------------------------------------
__global__ void prep_kernel(const float* __restrict__ x, bf16* __restrict__ y,
                            const float* __restrict__ W, bf16* __restrict__ Wt) {
  __shared__ float tile[32][33];
  const int tid = threadIdx.x;
  if (blockIdx.x < 3072) {
    size_t i = ((size_t)blockIdx.x * 256 + tid) * 8;
    float4 a = *(const float4*)(x + i);
    float4 b = *(const float4*)(x + i + 4);
    bf16x8 o;
    o[0] = (bf16)a.x; o[1] = (bf16)a.y; o[2] = (bf16)a.z; o[3] = (bf16)a.w;
    o[4] = (bf16)b.x; o[5] = (bf16)b.y; o[6] = (bf16)b.z; o[7] = (bf16)b.w;
    *(bf16x8*)(y + i) = o;
  } else {
    const int bid = blockIdx.x - 3072;        // 0..1727
    const int tx = tid & 31, ty = tid >> 5;   // 32 x 8
    const int n0 = (bid % 72) * 32, k0 = (bid / 72) * 32;
#pragma unroll
    for (int r = 0; r < 4; ++r)
      tile[ty + r * 8][tx] = W[(size_t)(k0 + ty + r * 8) * 2304 + n0 + tx];
    __syncthreads();
#pragma unroll
    for (int r = 0; r < 4; ++r)
      Wt[(size_t)(n0 + ty + r * 8) * 768 + k0 + tx] = (bf16)tile[tx][ty + r * 8];
  }
}

// ---------------------------------------------------------------------------
// QKV GEMM v3 (R6-measured 42.3 us steady): 128x128 tile, BK=64,
//   XCD swizzle (FETCH 70->48 MB, measured R5) + counted-vmcnt two-barrier
//   K-loop (46->42.3 us, measured R6).
// ---------------------------------------------------------------------------
__global__ void qkv_gemm_kernel(const bf16* __restrict__ A, const bf16* __restrict__ Bw,
                                const float* __restrict__ bias,
                                bf16* __restrict__ Qo, bf16* __restrict__ Ko,
                                bf16* __restrict__ Vo) {
  __shared__ __align__(16) char lds[65536];   // 2 x (A 16KB + B 16KB)

  const int tid  = threadIdx.x;
  const int wave = tid >> 6, lane = tid & 63;
  const int quad = lane >> 4, mn = lane & 15;
  const int wr = wave >> 1, wc = wave & 1;

  // XCD swizzle: orig dispatch id -> contiguous per-XCD chunk (144 blocks)
  const int orig = blockIdx.y * 18 + blockIdx.x;   // hw flat id (x fastest)
  const int swz  = (orig & 7) * 144 + (orig >> 3); // 1152 = 8 * 144, bijective
  const int m0 = (swz / 18) * 128;
  const int n0 = (swz % 18) * 128;

  f32x4 acc[4][4] = {};

  const int lrow = lane >> 3;           // 0..7  (row within 8-row group)
  const int cg   = (lane & 7) ^ lrow;   // global 16B-chunk index (swizzled)

  auto stage = [&](int kt, char* buf) {
    char* Al = buf;
    char* Bl = buf + 16384;
#pragma unroll
    for (int u = 0; u < 4; ++u) {
      const int t   = wave * 4 + u;      // 8-row group 0..15
      const int row = t * 8 + lrow;      // tile row 0..127
      async16(Al + t * 1024 + lane * 16,
              A  + (size_t)(m0 + row) * 768 + kt + cg * 8);
      async16(Bl + t * 1024 + lane * 16,
              Bw + (size_t)(n0 + row) * 768 + kt + cg * 8);
    }
  };

#define SCHED0() __builtin_amdgcn_sched_barrier(0)

  stage(0, lds); SCHED0();

  for (int j = 0; j < 12; ++j) {
    // BAR-A: all waves finished iter j-1 LDS reads (WAR gate for buf (j+1)&1)
    asm volatile("s_waitcnt lgkmcnt(0)" ::: "memory"); SCHED0();
    __builtin_amdgcn_s_barrier(); SCHED0();
    if (j < 11) { stage((j + 1) * 64, lds + ((j + 1) & 1) * 32768); SCHED0(); }
    // complete own stage j (8 loads); leave stage j+1 in flight
    if (j < 11) { asm volatile("s_waitcnt vmcnt(8)" ::: "memory"); }
    else        { asm volatile("s_waitcnt vmcnt(0)" ::: "memory"); }
    SCHED0();
    __builtin_amdgcn_s_barrier(); SCHED0();   // BAR-B: publish stage j

    char* Al = lds + (j & 1) * 32768;
    char* Bl = Al + 16384;

#pragma unroll
    for (int s = 0; s < 2; ++s) {        // two K=32 steps within BK=64
      bf16x8 af[4], bfr[4];
      const int csw = ((s * 4 + quad) ^ (mn & 7)) * 16;  // swizzled chunk offset
#pragma unroll
      for (int i = 0; i < 4; ++i) {
        af[i]  = *(const bf16x8*)(Al + (wr * 64 + i * 16 + mn) * 128 + csw);
        bfr[i] = *(const bf16x8*)(Bl + (wc * 64 + i * 16 + mn) * 128 + csw);
      }
#pragma unroll
      for (int i = 0; i < 4; ++i)
#pragma unroll
        for (int jj = 0; jj < 4; ++jj)
          acc[i][jj] = __builtin_amdgcn_mfma_f32_16x16x32_bf16(af[i], bfr[jj], acc[i][jj], 0, 0, 0);
    }
  }

#undef SCHED0

  // epilogue
  const int ng    = n0 + wc * 64;
  const int third = ng / 768;           // 0=Q 1=K 2=V
  const int nmod  = ng % 768;
  const float sc  = (third == 0) ? ATT_SCALE : 1.0f;
#pragma unroll
  for (int ct = 0; ct < 4; ++ct) {
    int n = nmod + ct * 16 + mn;
    int h = n >> 6, d = n & 63;
    float bv = bias[third * 768 + n];
#pragma unroll
    for (int rt = 0; rt < 4; ++rt) {
      int m  = m0 + wr * 64 + rt * 16 + quad * 4;
      int b  = m >> 10, t0 = m & 1023;
      size_t bh = (size_t)b * 12 + h;
      if (third == 2) {
        bf16x4 pk;
#pragma unroll
        for (int r = 0; r < 4; ++r) pk[r] = (bf16)(acc[rt][ct][r] + bv);
        *(bf16x4*)(Vo + (bh * 64 + d) * 1024 + t0) = pk;   // V^T
      } else {
        bf16* dst = (third == 0 ? Qo : Ko) + (bh * 1024 + t0) * 64 + d;
#pragma unroll
        for (int r = 0; r < 4; ++r) dst[(size_t)r * 64] = (bf16)((acc[rt][ct][r] + bv) * sc);
      }
    }
  }
}

// ---------------------------------------------------------------------------
// Attention v7 (R6-measured best config, reverted from v11): K+V DMA-staged,
//   counted-vmcnt prefetch at distance 1, double-buffered KV, 48KB LDS ->
//   3 blocks/CU, 768 blocks = one residency round. R12 A/B closed the XCD-
//   swizzle question: 146.6 (swizzle) vs 142.4 (none) -> neutral-to-negative
//   (K/V is L3-fit; cross-XCD re-fetch was already cheap). Dataflow question
//   closed earlier: v7 (DMA both) ~40 > v10 (V per-lane) 50.5 > v8 (all
//   per-lane) 81 us.
//   Per-iter two-barrier phase:
//     lgkm-drain; BAR-A  (closes iter j-1 reads -> WAR gate)
//     stage(j+1) -> buf (j+1)&1
//     vmcnt(4)           (own stage j complete; j+1 stays in flight)
//     BAR-B              (publishes ALL waves' stage j)
//     compute on buf j&1 (S rows wave-private, no barrier inside)
//   vmcnt(0) only at the last iteration (pipeline provably starved).
// ---------------------------------------------------------------------------
__global__ __launch_bounds__(256, 3)
void attn_kernel(const bf16* __restrict__ Q, const bf16* __restrict__ K,
                 const bf16* __restrict__ Vt, float* __restrict__ out) {
  __shared__ __align__(16) char lds[49152];
  // buf c at lds + c*16384 (c = j&1): K 64x128B then V 64x128B (XOR-swizzled)
  char* ldsS = lds + 32768;              // 128 rows x 128B (A-half, B-half)

  const int tid  = threadIdx.x;
  const int wave = tid >> 6, lane = tid & 63;
  const int quad = lane >> 4, mn = lane & 15;
  const int bh  = blockIdx.x;
  const int qta = blockIdx.y;            // 0..7
  const int qtb = 15 - qta;              // 8..15
  const int qa0 = qta * 64, qb0 = qtb * 64;

  const bf16* Qg  = Q  + (size_t)bh * 65536;
  const bf16* Kg0 = K  + (size_t)bh * 65536;
  const bf16* Vg0 = Vt + (size_t)bh * 65536;

#define SCHED0() __builtin_amdgcn_sched_barrier(0)

  // Q fragments: lane mn -> row base+mn, d = quad*8.. / 32+quad*8..
  bf16x8 qfA[2], qfB[2];
  {
    const bf16* ra = Qg + (size_t)(qa0 + wave * 16 + mn) * 64;
    qfA[0] = *(const bf16x8*)(ra + quad * 8);
    qfA[1] = *(const bf16x8*)(ra + 32 + quad * 8);
    const bf16* rb = Qg + (size_t)(qb0 + wave * 16 + mn) * 64;
    qfB[0] = *(const bf16x8*)(rb + quad * 8);
    qfB[1] = *(const bf16x8*)(rb + 32 + quad * 8);
  }
  SCHED0();   // pin Q-loads before the staged DMA (vmcnt order discipline)

  f32x4 yA[4] = {}, yB[4] = {};

  const int lrow = lane >> 3;            // 0..7
  const int cg   = (lane & 7) ^ lrow;    // swizzled global chunk

  auto stageKV = [&](int j, char* buf) {
#pragma unroll
    for (int u2 = 0; u2 < 2; ++u2) {
      const int u   = wave * 2 + u2;     // 8-row group 0..7
      const int row = u * 8 + lrow;      // 0..63
      async16(buf + u * 1024 + lane * 16,
              Kg0 + (size_t)(j * 64 + row) * 64 + cg * 8);
      async16(buf + 8192 + u * 1024 + lane * 16,
              Vg0 + (size_t)row * 1024 + j * 64 + cg * 8);
    }
  };

  const int srow = (wave * 16 + mn) * 128;   // within a half (half adds 8192)

  // prologue: stage tile 0 only (stage 1 issued inside iter 0 after BAR-A)
  stageKV(0, lds);  SCHED0();

  for (int j = 0; j <= qtb; ++j) {
    // drain own ds ops, then BAR-A: all waves finished iter j-1 LDS reads
    asm volatile("s_waitcnt lgkmcnt(0)" ::: "memory"); SCHED0();
    __builtin_amdgcn_s_barrier(); SCHED0();
    if (j < qtb) { stageKV(j + 1, lds + ((j + 1) & 1) * 16384); SCHED0(); }
    // complete own stage j (leave stage j+1 in flight), then publish
    if (j < qtb) { asm volatile("s_waitcnt vmcnt(4)" ::: "memory"); }
    else         { asm volatile("s_waitcnt vmcnt(0)" ::: "memory"); }
    SCHED0();
    __builtin_amdgcn_s_barrier(); SCHED0();

    char* bK = lds + (j & 1) * 16384;
    char* bV = bK + 8192;

    // hoisted K/V fragments (shared by both halves)
    bf16x8 kf[4][2], vf[4][2];
    const int sw = mn & 7;
#pragma unroll
    for (int ct = 0; ct < 4; ++ct) {
      const int ro = (ct * 16 + mn) * 128;
      kf[ct][0] = *(const bf16x8*)(bK + ro + ((quad)     ^ sw) * 16);
      kf[ct][1] = *(const bf16x8*)(bK + ro + ((4 + quad) ^ sw) * 16);
      vf[ct][0] = *(const bf16x8*)(bV + ro + ((quad)     ^ sw) * 16);
      vf[ct][1] = *(const bf16x8*)(bV + ro + ((4 + quad) ^ sw) * 16);
    }

    auto qk_half = [&](const bf16x8* qf, int half, int qrow, bool diag) {
      // S^T = K Q^T: lane holds (kk = j*64+ct*16+quad*4+r, q = qrow=base+mn)
#pragma unroll
      for (int ct = 0; ct < 4; ++ct) {
        f32x4 a = {};
        a = __builtin_amdgcn_mfma_f32_16x16x32_bf16(kf[ct][0], qf[0], a, 0, 0, 0);
        a = __builtin_amdgcn_mfma_f32_16x16x32_bf16(kf[ct][1], qf[1], a, 0, 0, 0);
        const int kkg = j * 64 + ct * 16 + quad * 4;
        bf16x4 pk;
#pragma unroll
        for (int r = 0; r < 4; ++r) {
          float v = a[r];
          v = v > 0.f ? v : 0.f;
          if (diag && kkg + r > qrow) v = 0.f;
          pk[r] = (bf16)v;
        }
        *(bf16x4*)(ldsS + half * 8192 + srow +
                   (((ct * 4 + quad) ^ (sw << 1)) & 15) * 8) = pk;
      }
    };
    auto sv_half = [&](f32x4* y, int half) {
#pragma unroll
      for (int kb = 0; kb < 2; ++kb) {
        bf16x8 sf = *(const bf16x8*)(ldsS + half * 8192 + srow +
                                     ((kb * 4 + quad) ^ sw) * 16);
#pragma unroll
        for (int ct = 0; ct < 4; ++ct)
          y[ct] = __builtin_amdgcn_mfma_f32_16x16x32_bf16(sf, vf[ct][kb], y[ct], 0, 0, 0);
      }
    };

    if (j <= qta) qk_half(qfA, 0, qa0 + wave * 16 + mn, j == qta);
    qk_half(qfB, 1, qb0 + wave * 16 + mn, j == qtb);
    if (j <= qta) sv_half(yA, 0);
    sv_half(yB, 1);
  }

#undef SCHED0

  // write out: out[b][t][h*64+d]; yacc: q = wave*16+quad*4+r, d = ct*16+mn
  const int b = bh / 12, h = bh % 12;
  {
    float* ob = out + ((size_t)b * 1024 + qa0 + wave * 16 + quad * 4) * 768 + h * 64;
#pragma unroll
    for (int ct = 0; ct < 4; ++ct)
#pragma unroll
      for (int r = 0; r < 4; ++r)
        ob[(size_t)r * 768 + ct * 16 + mn] = yA[ct][r];
  }
  {
    float* ob = out + ((size_t)b * 1024 + qb0 + wave * 16 + quad * 4) * 768 + h * 64;
#pragma unroll
    for (int ct = 0; ct < 4; ++ct)
#pragma unroll
      for (int r = 0; r < 4; ++r)
        ob[(size_t)r * 768 + ct * 16 + mn] = yB[ct][r];
  }
}

// ---------------------------------------------------------------------------
extern "C" void kernel_launch(void* const* d_in, const int* in_sizes, int n_in,
                              void* d_out, int out_size, void* d_ws, size_t ws_size,
                              hipStream_t stream) {
  const float* x    = (const float*)d_in[0];   // [8,1024,768]
  const float* W    = (const float*)d_in[1];   // [768,2304]
  const float* bias = (const float*)d_in[2];   // [2304]
  float* out = (float*)d_out;                  // [8,1024,768]

  char* ws = (char*)d_ws;
  bf16* xb = (bf16*)(ws);                      // 8192*768
  bf16* Wt = (bf16*)(ws + 12582912);           // 2304*768
  bf16* Qb = (bf16*)(ws + 16121856);           // 96*1024*64
  bf16* Kb = (bf16*)(ws + 28704768);           // 96*1024*64
  bf16* Vb = (bf16*)(ws + 41287680);           // 96*64*1024 (V^T)

  prep_kernel<<<4800, 256, 0, stream>>>(x, xb, W, Wt);
  qkv_gemm_kernel<<<dim3(18, 64), 256, 0, stream>>>(xb, Wt, bias, Qb, Kb, Vb);
  attn_kernel<<<dim3(96, 8), 256, 0, stream>>>(Qb, Kb, Vb, out);
}

// Round 14
// 138.231 us; speedup vs baseline: 1.5617x; 1.0283x over previous
//
#include <hip/hip_runtime.h>
#include <stdint.h>

typedef __bf16 bf16;
typedef __attribute__((ext_vector_type(8))) __bf16 bf16x8;
typedef __attribute__((ext_vector_type(4))) __bf16 bf16x4;
typedef __attribute__((ext_vector_type(4))) float  f32x4;

#define ATT_SCALE 0.125f   // 1/sqrt(64), folded into Q at GEMM epilogue

// ---------------------------------------------------------------------------
// async 16B global -> LDS (wave-uniform LDS base + lane*16, per-lane gaddr)
// ---------------------------------------------------------------------------
__device__ __forceinline__ void async16(void* lds, const void* g) {
  __builtin_amdgcn_global_load_lds(
      (__attribute__((address_space(1))) void*)(void*)g,
      (__attribute__((address_space(3))) void*)lds,
      16, 0, 0);
}

// ---------------------------------------------------------------------------
// Fused prep: blocks [0,3072) convert x fp32->bf16 (8 elems/thread);
//             blocks [3072,4800) transpose W [768x2304] fp32 -> Wt bf16.
// ---------------------------------------------------------------------------
__global__ void prep_kernel(const float* __restrict__ x, bf16* __restrict__ y,
                            const float* __restrict__ W, bf16* __restrict__ Wt) {
  __shared__ float tile[32][33];
  const int tid = threadIdx.x;
  if (blockIdx.x < 3072) {
    size_t i = ((size_t)blockIdx.x * 256 + tid) * 8;
    float4 a = *(const float4*)(x + i);
    float4 b = *(const float4*)(x + i + 4);
    bf16x8 o;
    o[0] = (bf16)a.x; o[1] = (bf16)a.y; o[2] = (bf16)a.z; o[3] = (bf16)a.w;
    o[4] = (bf16)b.x; o[5] = (bf16)b.y; o[6] = (bf16)b.z; o[7] = (bf16)b.w;
    *(bf16x8*)(y + i) = o;
  } else {
    const int bid = blockIdx.x - 3072;        // 0..1727
    const int tx = tid & 31, ty = tid >> 5;   // 32 x 8
    const int n0 = (bid % 72) * 32, k0 = (bid / 72) * 32;
#pragma unroll
    for (int r = 0; r < 4; ++r)
      tile[ty + r * 8][tx] = W[(size_t)(k0 + ty + r * 8) * 2304 + n0 + tx];
    __syncthreads();
#pragma unroll
    for (int r = 0; r < 4; ++r)
      Wt[(size_t)(n0 + ty + r * 8) * 768 + k0 + tx] = (bf16)tile[tx][ty + r * 8];
  }
}

// ---------------------------------------------------------------------------
// QKV GEMM v4 = v3 skeleton (XCD swizzle + counted-vmcnt two-barrier loop,
//   both measured wins) at 512 threads / 8 waves per block.
//   v3 ran 8 waves/CU (2 blocks x 4 waves) = 2 waves/SIMD — minimal latency
//   hiding; MfmaUtil 19%, Occ 17%. v4: same 128x128 tile, same 64KB LDS
//   (2 blocks/CU), same staging addresses (t = wave*2+u covers the same 16
//   row-groups), same XOR swizzle — but wave grid 2x4, per-wave output
//   64x32 (acc[4][2]) -> 16 waves/CU = 4/SIMD; per-wave ds_read->MFMA
//   chains halve. vmcnt re-counted: 4 loads/wave/stage -> vmcnt(4) mid-loop
//   completes exactly stage j; vmcnt(0) at the last iteration.
// ---------------------------------------------------------------------------
__global__ __launch_bounds__(512, 4)
void qkv_gemm_kernel(const bf16* __restrict__ A, const bf16* __restrict__ Bw,
                     const float* __restrict__ bias,
                     bf16* __restrict__ Qo, bf16* __restrict__ Ko,
                     bf16* __restrict__ Vo) {
  __shared__ __align__(16) char lds[65536];   // 2 x (A 16KB + B 16KB)

  const int tid  = threadIdx.x;
  const int wave = tid >> 6, lane = tid & 63;
  const int quad = lane >> 4, mn = lane & 15;
  const int wr = wave >> 2, wc = wave & 3;    // 2 x 4 wave grid

  // XCD swizzle: orig dispatch id -> contiguous per-XCD chunk (144 blocks)
  const int orig = blockIdx.y * 18 + blockIdx.x;   // hw flat id (x fastest)
  const int swz  = (orig & 7) * 144 + (orig >> 3); // 1152 = 8 * 144, bijective
  const int m0 = (swz / 18) * 128;
  const int n0 = (swz % 18) * 128;

  f32x4 acc[4][2] = {};

  const int lrow = lane >> 3;           // 0..7  (row within 8-row group)
  const int cg   = (lane & 7) ^ lrow;   // global 16B-chunk index (swizzled)

  auto stage = [&](int kt, char* buf) {
    char* Al = buf;
    char* Bl = buf + 16384;
#pragma unroll
    for (int u = 0; u < 2; ++u) {
      const int t   = wave * 2 + u;      // 8-row group 0..15
      const int row = t * 8 + lrow;      // tile row 0..127
      async16(Al + t * 1024 + lane * 16,
              A  + (size_t)(m0 + row) * 768 + kt + cg * 8);
      async16(Bl + t * 1024 + lane * 16,
              Bw + (size_t)(n0 + row) * 768 + kt + cg * 8);
    }
  };

#define SCHED0() __builtin_amdgcn_sched_barrier(0)

  stage(0, lds); SCHED0();

  for (int j = 0; j < 12; ++j) {
    // BAR-A: all waves finished iter j-1 LDS reads (WAR gate for buf (j+1)&1)
    asm volatile("s_waitcnt lgkmcnt(0)" ::: "memory"); SCHED0();
    __builtin_amdgcn_s_barrier(); SCHED0();
    if (j < 11) { stage((j + 1) * 64, lds + ((j + 1) & 1) * 32768); SCHED0(); }
    // complete own stage j (4 loads); leave stage j+1 (4 loads) in flight
    if (j < 11) { asm volatile("s_waitcnt vmcnt(4)" ::: "memory"); }
    else        { asm volatile("s_waitcnt vmcnt(0)" ::: "memory"); }
    SCHED0();
    __builtin_amdgcn_s_barrier(); SCHED0();   // BAR-B: publish stage j

    char* Al = lds + (j & 1) * 32768;
    char* Bl = Al + 16384;

#pragma unroll
    for (int s = 0; s < 2; ++s) {        // two K=32 steps within BK=64
      bf16x8 af[4], bfr[2];
      const int csw = ((s * 4 + quad) ^ (mn & 7)) * 16;  // swizzled chunk offset
#pragma unroll
      for (int i = 0; i < 4; ++i)
        af[i]  = *(const bf16x8*)(Al + (wr * 64 + i * 16 + mn) * 128 + csw);
#pragma unroll
      for (int jb = 0; jb < 2; ++jb)
        bfr[jb] = *(const bf16x8*)(Bl + (wc * 32 + jb * 16 + mn) * 128 + csw);
#pragma unroll
      for (int i = 0; i < 4; ++i)
#pragma unroll
        for (int jb = 0; jb < 2; ++jb)
          acc[i][jb] = __builtin_amdgcn_mfma_f32_16x16x32_bf16(af[i], bfr[jb], acc[i][jb], 0, 0, 0);
    }
  }

#undef SCHED0

  // epilogue: rows m0 + wr*64 + rt*16 + quad*4 + r; cols n0 + wc*32 + ct*16 + mn
  const int ng    = n0 + wc * 32;
  const int third = ng / 768;           // 0=Q 1=K 2=V (32-col wave range never spans)
  const int nmod  = ng % 768;
  const float sc  = (third == 0) ? ATT_SCALE : 1.0f;
#pragma unroll
  for (int ct = 0; ct < 2; ++ct) {
    int n = nmod + ct * 16 + mn;
    int h = n >> 6, d = n & 63;
    float bv = bias[third * 768 + n];
#pragma unroll
    for (int rt = 0; rt < 4; ++rt) {
      int m  = m0 + wr * 64 + rt * 16 + quad * 4;
      int b  = m >> 10, t0 = m & 1023;
      size_t bh = (size_t)b * 12 + h;
      if (third == 2) {
        bf16x4 pk;
#pragma unroll
        for (int r = 0; r < 4; ++r) pk[r] = (bf16)(acc[rt][ct][r] + bv);
        *(bf16x4*)(Vo + (bh * 64 + d) * 1024 + t0) = pk;   // V^T
      } else {
        bf16* dst = (third == 0 ? Qo : Ko) + (bh * 1024 + t0) * 64 + d;
#pragma unroll
        for (int r = 0; r < 4; ++r) dst[(size_t)r * 64] = (bf16)((acc[rt][ct][r] + bv) * sc);
      }
    }
  }
}

// ---------------------------------------------------------------------------
// Attention v7 (R6/R13-measured best config, unchanged): K+V DMA-staged,
//   counted-vmcnt prefetch at distance 1, double-buffered KV, 48KB LDS ->
//   3 blocks/CU, 768 blocks = one residency round. Closed questions:
//   dataflow (DMA both ~40 > V-per-lane 50.5 > all-per-lane 81 us) and
//   XCD swizzle (neutral-to-negative, R12; K/V is L3-fit).
// ---------------------------------------------------------------------------
__global__ __launch_bounds__(256, 3)
void attn_kernel(const bf16* __restrict__ Q, const bf16* __restrict__ K,
                 const bf16* __restrict__ Vt, float* __restrict__ out) {
  __shared__ __align__(16) char lds[49152];
  // buf c at lds + c*16384 (c = j&1): K 64x128B then V 64x128B (XOR-swizzled)
  char* ldsS = lds + 32768;              // 128 rows x 128B (A-half, B-half)

  const int tid  = threadIdx.x;
  const int wave = tid >> 6, lane = tid & 63;
  const int quad = lane >> 4, mn = lane & 15;
  const int bh  = blockIdx.x;
  const int qta = blockIdx.y;            // 0..7
  const int qtb = 15 - qta;              // 8..15
  const int qa0 = qta * 64, qb0 = qtb * 64;

  const bf16* Qg  = Q  + (size_t)bh * 65536;
  const bf16* Kg0 = K  + (size_t)bh * 65536;
  const bf16* Vg0 = Vt + (size_t)bh * 65536;

#define SCHED0() __builtin_amdgcn_sched_barrier(0)

  // Q fragments: lane mn -> row base+mn, d = quad*8.. / 32+quad*8..
  bf16x8 qfA[2], qfB[2];
  {
    const bf16* ra = Qg + (size_t)(qa0 + wave * 16 + mn) * 64;
    qfA[0] = *(const bf16x8*)(ra + quad * 8);
    qfA[1] = *(const bf16x8*)(ra + 32 + quad * 8);
    const bf16* rb = Qg + (size_t)(qb0 + wave * 16 + mn) * 64;
    qfB[0] = *(const bf16x8*)(rb + quad * 8);
    qfB[1] = *(const bf16x8*)(rb + 32 + quad * 8);
  }
  SCHED0();   // pin Q-loads before the staged DMA (vmcnt order discipline)

  f32x4 yA[4] = {}, yB[4] = {};

  const int lrow = lane >> 3;            // 0..7
  const int cg   = (lane & 7) ^ lrow;    // swizzled global chunk

  auto stageKV = [&](int j, char* buf) {
#pragma unroll
    for (int u2 = 0; u2 < 2; ++u2) {
      const int u   = wave * 2 + u2;     // 8-row group 0..7
      const int row = u * 8 + lrow;      // 0..63
      async16(buf + u * 1024 + lane * 16,
              Kg0 + (size_t)(j * 64 + row) * 64 + cg * 8);
      async16(buf + 8192 + u * 1024 + lane * 16,
              Vg0 + (size_t)row * 1024 + j * 64 + cg * 8);
    }
  };

  const int srow = (wave * 16 + mn) * 128;   // within a half (half adds 8192)

  // prologue: stage tile 0 only (stage 1 issued inside iter 0 after BAR-A)
  stageKV(0, lds);  SCHED0();

  for (int j = 0; j <= qtb; ++j) {
    // drain own ds ops, then BAR-A: all waves finished iter j-1 LDS reads
    asm volatile("s_waitcnt lgkmcnt(0)" ::: "memory"); SCHED0();
    __builtin_amdgcn_s_barrier(); SCHED0();
    if (j < qtb) { stageKV(j + 1, lds + ((j + 1) & 1) * 16384); SCHED0(); }
    // complete own stage j (leave stage j+1 in flight), then publish
    if (j < qtb) { asm volatile("s_waitcnt vmcnt(4)" ::: "memory"); }
    else         { asm volatile("s_waitcnt vmcnt(0)" ::: "memory"); }
    SCHED0();
    __builtin_amdgcn_s_barrier(); SCHED0();

    char* bK = lds + (j & 1) * 16384;
    char* bV = bK + 8192;

    // hoisted K/V fragments (shared by both halves)
    bf16x8 kf[4][2], vf[4][2];
    const int sw = mn & 7;
#pragma unroll
    for (int ct = 0; ct < 4; ++ct) {
      const int ro = (ct * 16 + mn) * 128;
      kf[ct][0] = *(const bf16x8*)(bK + ro + ((quad)     ^ sw) * 16);
      kf[ct][1] = *(const bf16x8*)(bK + ro + ((4 + quad) ^ sw) * 16);
      vf[ct][0] = *(const bf16x8*)(bV + ro + ((quad)     ^ sw) * 16);
      vf[ct][1] = *(const bf16x8*)(bV + ro + ((4 + quad) ^ sw) * 16);
    }

    auto qk_half = [&](const bf16x8* qf, int half, int qrow, bool diag) {
      // S^T = K Q^T: lane holds (kk = j*64+ct*16+quad*4+r, q = qrow=base+mn)
#pragma unroll
      for (int ct = 0; ct < 4; ++ct) {
        f32x4 a = {};
        a = __builtin_amdgcn_mfma_f32_16x16x32_bf16(kf[ct][0], qf[0], a, 0, 0, 0);
        a = __builtin_amdgcn_mfma_f32_16x16x32_bf16(kf[ct][1], qf[1], a, 0, 0, 0);
        const int kkg = j * 64 + ct * 16 + quad * 4;
        bf16x4 pk;
#pragma unroll
        for (int r = 0; r < 4; ++r) {
          float v = a[r];
          v = v > 0.f ? v : 0.f;
          if (diag && kkg + r > qrow) v = 0.f;
          pk[r] = (bf16)v;
        }
        *(bf16x4*)(ldsS + half * 8192 + srow +
                   (((ct * 4 + quad) ^ (sw << 1)) & 15) * 8) = pk;
      }
    };
    auto sv_half = [&](f32x4* y, int half) {
#pragma unroll
      for (int kb = 0; kb < 2; ++kb) {
        bf16x8 sf = *(const bf16x8*)(ldsS + half * 8192 + srow +
                                     ((kb * 4 + quad) ^ sw) * 16);
#pragma unroll
        for (int ct = 0; ct < 4; ++ct)
          y[ct] = __builtin_amdgcn_mfma_f32_16x16x32_bf16(sf, vf[ct][kb], y[ct], 0, 0, 0);
      }
    };

    if (j <= qta) qk_half(qfA, 0, qa0 + wave * 16 + mn, j == qta);
    qk_half(qfB, 1, qb0 + wave * 16 + mn, j == qtb);
    if (j <= qta) sv_half(yA, 0);
    sv_half(yB, 1);
  }

#undef SCHED0

  // write out: out[b][t][h*64+d]; yacc: q = wave*16+quad*4+r, d = ct*16+mn
  const int b = bh / 12, h = bh % 12;
  {
    float* ob = out + ((size_t)b * 1024 + qa0 + wave * 16 + quad * 4) * 768 + h * 64;
#pragma unroll
    for (int ct = 0; ct < 4; ++ct)
#pragma unroll
      for (int r = 0; r < 4; ++r)
        ob[(size_t)r * 768 + ct * 16 + mn] = yA[ct][r];
  }
  {
    float* ob = out + ((size_t)b * 1024 + qb0 + wave * 16 + quad * 4) * 768 + h * 64;
#pragma unroll
    for (int ct = 0; ct < 4; ++ct)
#pragma unroll
      for (int r = 0; r < 4; ++r)
        ob[(size_t)r * 768 + ct * 16 + mn] = yB[ct][r];
  }
}

// ---------------------------------------------------------------------------
extern "C" void kernel_launch(void* const* d_in, const int* in_sizes, int n_in,
                              void* d_out, int out_size, void* d_ws, size_t ws_size,
                              hipStream_t stream) {
  const float* x    = (const float*)d_in[0];   // [8,1024,768]
  const float* W    = (const float*)d_in[1];   // [768,2304]
  const float* bias = (const float*)d_in[2];   // [2304]
  float* out = (float*)d_out;                  // [8,1024,768]

  char* ws = (char*)d_ws;
  bf16* xb = (bf16*)(ws);                      // 8192*768
  bf16* Wt = (bf16*)(ws + 12582912);           // 2304*768
  bf16* Qb = (bf16*)(ws + 16121856);           // 96*1024*64
  bf16* Kb = (bf16*)(ws + 28704768);           // 96*1024*64
  bf16* Vb = (bf16*)(ws + 41287680);           // 96*64*1024 (V^T)

  prep_kernel<<<4800, 256, 0, stream>>>(x, xb, W, Wt);
  qkv_gemm_kernel<<<dim3(18, 64), 512, 0, stream>>>(xb, Wt, bias, Qb, Kb, Vb);
  attn_kernel<<<dim3(96, 8), 256, 0, stream>>>(Qb, Kb, Vb, out);
}